// Round 1
// 690.418 us; speedup vs baseline: 1.1712x; 1.1712x over previous
//
#include <hip/hip_runtime.h>
#include <hip/hip_bf16.h>
#include <math.h>

typedef __attribute__((ext_vector_type(4))) float f32x4;
typedef __attribute__((ext_vector_type(8))) short bf16x8;
typedef __attribute__((ext_vector_type(4))) short s16x4;

#define M_TOT   8192
#define OFF_MCONF 33554432LL                 // 8192*4096
#define OFF_MK0   33562624LL
#define OFF_MK1   33579008LL
#define OFF_VALID 33595392LL
#define SIM_SCALE 0.10416666666666667f       // 1/(96*0.1)

__device__ __forceinline__ short f2bf(float v) {
    __hip_bfloat16 h = __float2bfloat16(v);
    return *reinterpret_cast<short*>(&h);
}

// ---------------------------------------------------------------------------
// K0: repack w1/w2 (oc,ic,ky,kx) f32 -> (oc, q=ky*3+kx, ic) bf16  (GEMM-B^T)
// ---------------------------------------------------------------------------
__global__ void wprep(const float* __restrict__ w1, const float* __restrict__ w2,
                      short* __restrict__ o1, short* __restrict__ o2) {
    int i = blockIdx.x * 256 + threadIdx.x;
    if (i >= 2 * 331776) return;
    const float* src = (i < 331776) ? w1 : w2;
    short* dst       = (i < 331776) ? o1 : o2;
    int o = (i < 331776) ? i : i - 331776;
    int oc = o / 1728, r = o % 1728;
    int q = r / 192, ic = r % 192;
    dst[o] = f2bf(src[oc * 1728 + ic * 9 + q]);
}

// ---------------------------------------------------------------------------
// K1: per-m 64x64 sim via 3-term split-bf16 MFMA (hi*hi + hi*lo + lo*hi),
//     conf = softmax_l * softmax_s, conf write, argmax -> mconf/valid +
//     mk0/mk1 coords. One block per m, 4 waves; wave w owns rows w*16..w*16+15
//     of the 64x64 output (4 MFMA tiles of 16x16, K=96).
//     LDS: bf16 hi/lo tiles at natural stride 96 (16B aligned, bank-uniform)
//     = 50.2 KB -> 3 blocks/CU (was 62 KB -> 2).
// ---------------------------------------------------------------------------
__global__ __launch_bounds__(256, 3) void stageA(const float* __restrict__ f0u,
                                                 const float* __restrict__ f1u,
                                                 const int* __restrict__ i_ids_c,
                                                 const int* __restrict__ j_ids_c,
                                                 float* __restrict__ out,
                                                 int* __restrict__ mkws) {
    __shared__ short h0s[6144], l0s[6144];   // f0: 64 rows x 96, hi/lo bf16
    __shared__ short h1s[6144], l1s[6144];   // f1
    __shared__ float Cpart[256];             // [wave][s] col partial sums
    __shared__ float rbv[4];
    __shared__ int   rbi[4];

    const int m = blockIdx.x;
    const int t = threadIdx.x;
    const int lane = t & 63, w = t >> 6;
    const int l15 = lane & 15, q = lane >> 4;

    // ---- stage f0/f1 into LDS as bf16 hi/lo split (RNE hi, RNE residual) ----
    const float* g0 = f0u + (size_t)m * 6144;
    const float* g1 = f1u + (size_t)m * 6144;
#pragma unroll
    for (int it = 0; it < 12; ++it) {
        const int i = it * 256 + t;           // uniform branch per iteration
        const bool first = (i < 1536);
        const int off = (first ? i : i - 1536) * 4;
        f32x4 v = *(const f32x4*)((first ? g0 : g1) + off);
        s16x4 hv, lv;
#pragma unroll
        for (int j = 0; j < 4; ++j) {
            __hip_bfloat16 hb = __float2bfloat16(v[j]);
            hv[j] = *reinterpret_cast<short*>(&hb);
            float r = v[j] - __bfloat162float(hb);
            __hip_bfloat16 lb = __float2bfloat16(r);
            lv[j] = *reinterpret_cast<short*>(&lb);
        }
        *(s16x4*)&(first ? h0s : h1s)[off] = hv;
        *(s16x4*)&(first ? l0s : l1s)[off] = lv;
    }
    __syncthreads();

    // ---- sim = f0 . f1^T via MFMA, 3-term split. A-frag row = w*16+l15,
    //      k-chunk = c*32 + q*8 (gemm_bt layout, m89/m92-verified). ----
    bf16x8 aH[3], aL[3];
    const int abase = (w * 16 + l15) * 96;
#pragma unroll
    for (int c = 0; c < 3; ++c) {
        aH[c] = *(const bf16x8*)&h0s[abase + c * 32 + q * 8];
        aL[c] = *(const bf16x8*)&l0s[abase + c * 32 + q * 8];
    }
    f32x4 acc[4] = {};
#pragma unroll
    for (int sj = 0; sj < 4; ++sj) {
        const int bbase = (sj * 16 + l15) * 96;
#pragma unroll
        for (int c = 0; c < 3; ++c) {
            bf16x8 bH = *(const bf16x8*)&h1s[bbase + c * 32 + q * 8];
            bf16x8 bL = *(const bf16x8*)&l1s[bbase + c * 32 + q * 8];
            acc[sj] = __builtin_amdgcn_mfma_f32_16x16x32_bf16(aH[c], bH, acc[sj], 0, 0, 0);
            acc[sj] = __builtin_amdgcn_mfma_f32_16x16x32_bf16(aH[c], bL, acc[sj], 0, 0, 0);
            acc[sj] = __builtin_amdgcn_mfma_f32_16x16x32_bf16(aL[c], bH, acc[sj], 0, 0, 0);
        }
    }

    // lane holds e[sj][r] for row = w*16 + q*4 + r, col s = sj*16 + l15
    float e[4][4];
    float rp[4] = {0.f, 0.f, 0.f, 0.f}, cp[4] = {0.f, 0.f, 0.f, 0.f};
#pragma unroll
    for (int sj = 0; sj < 4; ++sj)
#pragma unroll
        for (int r = 0; r < 4; ++r) {
            float v = __expf(acc[sj][r] * SIM_SCALE);
            e[sj][r] = v;
            rp[r] += v;
            cp[sj] += v;
        }
    // row sums (over s): rows are wave-exclusive; butterfly over the 16 lanes
    // sharing q (masks 1,2,4,8) completes the sum in-register.
#pragma unroll
    for (int mk = 1; mk <= 8; mk <<= 1)
#pragma unroll
        for (int r = 0; r < 4; ++r) rp[r] += __shfl_xor(rp[r], mk);
    // col partials (over this wave's 16 rows): butterfly over q (masks 16,32)
#pragma unroll
    for (int mk = 16; mk <= 32; mk <<= 1)
#pragma unroll
        for (int sj = 0; sj < 4; ++sj) cp[sj] += __shfl_xor(cp[sj], mk);
    if (q == 0) {
#pragma unroll
        for (int sj = 0; sj < 4; ++sj) Cpart[w * 64 + sj * 16 + l15] = cp[sj];
    }
    __syncthreads();

    float ivr[4], ivc[4];
#pragma unroll
    for (int r = 0; r < 4; ++r) ivr[r] = 1.0f / rp[r];
#pragma unroll
    for (int sj = 0; sj < 4; ++sj) {
        const int s = sj * 16 + l15;
        ivc[sj] = 1.0f / (Cpart[s] + Cpart[64 + s] + Cpart[128 + s] + Cpart[192 + s]);
    }

    // conf write + thread-local argmax (tie -> lowest flat index, as jnp.argmax)
    float bestv = -1.0f;
    int besti = 0;
    float* cbase = out + (size_t)m * 4096;
#pragma unroll
    for (int sj = 0; sj < 4; ++sj) {
        const int s = sj * 16 + l15;
        const float is = ivc[sj];
#pragma unroll
        for (int r = 0; r < 4; ++r) {
            const int row = w * 16 + q * 4 + r;
            const float ev = e[sj][r];
            const float c = (ev * ivr[r]) * (ev * is);
            cbase[row * 64 + s] = c;
            const int fi = row * 64 + s;
            if (c > bestv || (c == bestv && fi < besti)) { bestv = c; besti = fi; }
        }
    }
    // wave argmax butterfly (value desc, index asc on ties)
#pragma unroll
    for (int mk = 1; mk <= 32; mk <<= 1) {
        float ov = __shfl_xor(bestv, mk);
        int   oi = __shfl_xor(besti, mk);
        if (ov > bestv || (ov == bestv && oi < besti)) { bestv = ov; besti = oi; }
    }
    if (lane == 0) { rbv[w] = bestv; rbi[w] = besti; }
    __syncthreads();
    if (t == 0) {
        float bv = rbv[0]; int bi = rbi[0];
#pragma unroll
        for (int g = 1; g < 4; ++g) {
            float v = rbv[g]; int idx = rbi[g];
            if (v > bv || (v == bv && idx < bi)) { bv = v; bi = idx; }
        }
        bool valid = bv > 0.01f;
        out[OFF_MCONF + m] = valid ? bv : 0.0f;
        out[OFF_VALID + m] = valid ? 1.0f : 0.0f;
        int il = bi >> 6, js = bi & 63;
        int ic0 = i_ids_c[m], jc0 = j_ids_c[m];
        mkws[m * 4 + 0] = (ic0 % 80) * 4 + (il & 7) - 4;   // mk0 x
        mkws[m * 4 + 1] = (ic0 / 80) * 4 + (il >> 3) - 4;  // mk0 y
        mkws[m * 4 + 2] = (jc0 % 80) * 4 + (js & 7) - 4;   // mk1 x
        mkws[m * 4 + 3] = (jc0 / 80) * 4 + (js >> 3) - 4;  // mk1 y
    }
}

// ---------------------------------------------------------------------------
// K2: fused gather + conv1(3x3,pad1) + conv2(3x3,valid) + conv3(1x1) + tanh.
// 16 matches per block. Patches in LDS as [m][slot 0..9][ic(192), stride 200]
// bf16 (slot 9 = zero row for im2col padding). conv1 = 144x192 GEMM, K=1728
// in q-major order; conv2 reuses LDS in-place as [row=m*9+p][oc, stride 200].
// ---------------------------------------------------------------------------
__global__ __launch_bounds__(256, 2) void stageB(const float* __restrict__ w0whole,
                                                 const float* __restrict__ w1whole,
                                                 const int* __restrict__ bids,
                                                 const int* __restrict__ mkws,
                                                 const short* __restrict__ w1b,
                                                 const short* __restrict__ w2b,
                                                 const float* __restrict__ w3,
                                                 float* __restrict__ out) {
    __shared__ short bufA[32000];        // 64 KB: patches, then conv1 output
    __shared__ float bufC[16 * 196];     // conv2 output (padded stride 196)
    __shared__ float xout[64];

    const int t = threadIdx.x;
    const int m0 = blockIdx.x * 16;
    const int lane = t & 63, wv = t >> 6;
    const int l16 = lane & 15, quad = lane >> 4;
    const int colb = wv * 48;

    // zero-slot (slot 9) per m
    for (int v = t; v < 16 * 200; v += 256) {
        int mm = v / 200, c = v % 200;
        bufA[mm * 2000 + 1800 + c] = 0;
    }
    // gather: 16 m * 2 img * 96 c * 3 dy = 9216 3-float row segments
    for (int seg = t; seg < 9216; seg += 256) {
        int c = seg % 96;
        int r = seg / 96;
        int dy = r % 3;
        int mi = r / 3;
        int img = mi & 1;
        int m_loc = mi >> 1;
        int mg = m0 + m_loc;
        int b = bids[mg];
        int mkx = mkws[mg * 4 + img * 2 + 0];
        int mky = mkws[mg * 4 + img * 2 + 1];
        int y = mky + dy - 1;
        const float* src = (img ? w1whole : w0whole) + (((size_t)b * 96 + c) * 320 + y) * 320;
        bool yok = (unsigned)y < 320u;
        short* dst = &bufA[m_loc * 2000 + dy * 3 * 200 + img * 96 + c];
#pragma unroll
        for (int dx = 0; dx < 3; ++dx) {
            int x = mkx + dx - 1;
            float v = (yok && (unsigned)x < 320u) ? src[x] : 0.0f;
            dst[dx * 200] = f2bf(v);
        }
    }
    __syncthreads();

    // ---- conv1: GEMM rows=(m*9+p) 144, cols=oc 192, K=(q,ic) 1728 ----
    int mbase[9], py[9], px[9];
#pragma unroll
    for (int rt = 0; rt < 9; ++rt) {
        int row = rt * 16 + l16;
        int mm = row / 9;
        int p = row - mm * 9;
        mbase[rt] = mm * 2000;
        py[rt] = p / 3;
        px[rt] = p - py[rt] * 3;
    }
    f32x4 acc1[9][3] = {};
#pragma unroll
    for (int q = 0; q < 9; ++q) {
        const int qy = q / 3, qx = q % 3;
        int aoff[9];
#pragma unroll
        for (int rt = 0; rt < 9; ++rt) {
            int y = py[rt] + qy - 1, x = px[rt] + qx - 1;
            bool ok = ((unsigned)y < 3u) && ((unsigned)x < 3u);
            int slot = ok ? (y * 3 + x) : 9;
            aoff[rt] = mbase[rt] + slot * 200 + quad * 8;
        }
#pragma unroll
        for (int kk = 0; kk < 6; ++kk) {
            const int kg = q * 192 + kk * 32 + quad * 8;
            bf16x8 bfr[3];
#pragma unroll
            for (int ct = 0; ct < 3; ++ct) {
                int n = colb + ct * 16 + l16;
                bfr[ct] = *(const bf16x8*)(w1b + n * 1728 + kg);
            }
            bf16x8 afr[9];
#pragma unroll
            for (int rt = 0; rt < 9; ++rt)
                afr[rt] = *(const bf16x8*)&bufA[aoff[rt] + kk * 32];
#pragma unroll
            for (int rt = 0; rt < 9; ++rt)
#pragma unroll
                for (int ct = 0; ct < 3; ++ct)
                    acc1[rt][ct] = __builtin_amdgcn_mfma_f32_16x16x32_bf16(
                        afr[rt], bfr[ct], acc1[rt][ct], 0, 0, 0);
        }
    }
    __syncthreads();
    // leaky-relu, bf16, store as [row][oc] stride 200 (in-place over patches)
#pragma unroll
    for (int rt = 0; rt < 9; ++rt)
#pragma unroll
        for (int ct = 0; ct < 3; ++ct)
#pragma unroll
            for (int r = 0; r < 4; ++r) {
                int row = rt * 16 + quad * 4 + r;
                int col = colb + ct * 16 + l16;
                float v = acc1[rt][ct][r];
                v = (v > 0.f) ? v : 0.01f * v;
                bufA[row * 200 + col] = f2bf(v);
            }
    __syncthreads();

    // ---- conv2: rows=m 16, cols=oc2 192, K=(p,ic2) 1728 ----
    f32x4 acc2[3] = {};
#pragma unroll 6
    for (int ks = 0; ks < 54; ++ks) {
        int k = ks * 32 + quad * 8;
        int p = k / 192;
        int ic = k - p * 192;
        bf16x8 a = *(const bf16x8*)&bufA[l16 * 1800 + p * 200 + ic];
#pragma unroll
        for (int ct = 0; ct < 3; ++ct) {
            int n = colb + ct * 16 + l16;
            bf16x8 b = *(const bf16x8*)(w2b + n * 1728 + k);
            acc2[ct] = __builtin_amdgcn_mfma_f32_16x16x32_bf16(a, b, acc2[ct], 0, 0, 0);
        }
    }
#pragma unroll
    for (int ct = 0; ct < 3; ++ct)
#pragma unroll
        for (int r = 0; r < 4; ++r) {
            int mrow = quad * 4 + r;
            int col = colb + ct * 16 + l16;
            float v = acc2[ct][r];
            v = (v > 0.f) ? v : 0.01f * v;
            bufC[mrow * 196 + col] = v;
        }
    __syncthreads();

    // ---- conv3 (1x1, 4 out channels) ----
    if (t < 64) {
        int mloc = t >> 2, j = t & 3;
        const float* wr = w3 + j * 192;
        const float* xr = &bufC[mloc * 196];
        float d = 0.f;
        for (int c = 0; c < 192; ++c) d += xr[c] * wr[c];
        xout[t] = d;
    }
    __syncthreads();
    if (t < 16) {
        int mg = m0 + t;
        float s0x = tanhf(xout[t * 4 + 0]) * 0.5f;
        float s0y = tanhf(xout[t * 4 + 1]) * 0.5f;
        float s1x = tanhf(xout[t * 4 + 2]) * 0.5f;
        float s1y = tanhf(xout[t * 4 + 3]) * 0.5f;
        float mk0x = (float)mkws[mg * 4 + 0], mk0y = (float)mkws[mg * 4 + 1];
        float mk1x = (float)mkws[mg * 4 + 2], mk1y = (float)mkws[mg * 4 + 3];
        out[OFF_MK0 + mg * 2 + 0] = (mk0x + s0x) * 2.0f;
        out[OFF_MK0 + mg * 2 + 1] = (mk0y + s0y) * 2.0f;
        out[OFF_MK1 + mg * 2 + 0] = (mk1x + s1x) * 2.0f;
        out[OFF_MK1 + mg * 2 + 1] = (mk1y + s1y) * 2.0f;
    }
}

extern "C" void kernel_launch(void* const* d_in, const int* in_sizes, int n_in,
                              void* d_out, int out_size, void* d_ws, size_t ws_size,
                              hipStream_t stream) {
    const float* f0u = (const float*)d_in[0];
    const float* f1u = (const float*)d_in[1];
    const float* f0w = (const float*)d_in[2];
    const float* f1w = (const float*)d_in[3];
    const int* bids  = (const int*)d_in[4];
    const int* iids  = (const int*)d_in[5];
    const int* jids  = (const int*)d_in[6];
    const float* w1  = (const float*)d_in[7];
    const float* w2  = (const float*)d_in[8];
    const float* w3  = (const float*)d_in[9];
    float* out = (float*)d_out;
    char* ws = (char*)d_ws;
    int* mkws  = (int*)ws;                          // 131072 B
    short* w1b = (short*)(ws + 131072);             // 663552 B
    short* w2b = (short*)(ws + 131072 + 663552);    // 663552 B

    wprep<<<dim3(2592), dim3(256), 0, stream>>>(w1, w2, w1b, w2b);
    stageA<<<dim3(8192), dim3(256), 0, stream>>>(f0u, f1u, iids, jids, out, mkws);
    stageB<<<dim3(512), dim3(256), 0, stream>>>(f0w, f1w, bids, mkws, w1b, w2b, w3, out);
}

// Round 2
// 665.315 us; speedup vs baseline: 1.2154x; 1.0377x over previous
//
#include <hip/hip_runtime.h>
#include <hip/hip_bf16.h>
#include <math.h>

typedef __attribute__((ext_vector_type(4))) float f32x4;
typedef __attribute__((ext_vector_type(8))) short bf16x8;
typedef __attribute__((ext_vector_type(4))) short s16x4;

#define M_TOT   8192
#define OFF_MCONF 33554432LL                 // 8192*4096
#define OFF_MK0   33562624LL
#define OFF_MK1   33579008LL
#define OFF_VALID 33595392LL
#define SIM_SCALE 0.10416666666666667f       // 1/(96*0.1)

// workspace layout
#define WS_MKWS   0
#define WS_W1B    131072
#define WS_W2B    794624
#define WS_NHWC   1458176ULL
#define NHWC_BYTES 79135488ULL               // 4 planes * 321*321*96 * 2B
// padded NHWC dims: [img*2+b][321][321][96] bf16, pixel (y+1, x+1)

__device__ __forceinline__ short f2bf(float v) {
    __hip_bfloat16 h = __float2bfloat16(v);
    return *reinterpret_cast<short*>(&h);
}

// ---------------------------------------------------------------------------
// K0: repack w1/w2 (oc,ic,ky,kx) f32 -> (oc, q=ky*3+kx, ic) bf16  (GEMM-B^T)
// ---------------------------------------------------------------------------
__global__ void wprep(const float* __restrict__ w1, const float* __restrict__ w2,
                      short* __restrict__ o1, short* __restrict__ o2) {
    int i = blockIdx.x * 256 + threadIdx.x;
    if (i >= 2 * 331776) return;
    const float* src = (i < 331776) ? w1 : w2;
    short* dst       = (i < 331776) ? o1 : o2;
    int o = (i < 331776) ? i : i - 331776;
    int oc = o / 1728, r = o % 1728;
    int q = r / 192, ic = r % 192;
    dst[o] = f2bf(src[oc * 1728 + ic * 9 + q]);
}

// ---------------------------------------------------------------------------
// K0b: zero the -1 border (y'==0 row and x'==0 column) of the NHWC buffer.
// 4 planes * 641 border pixels = 2564 pixels, 96ch (192B) each.
// ---------------------------------------------------------------------------
__global__ void zborder(short* __restrict__ nhwc) {
    int tid = blockIdx.x * 256 + threadIdx.x;
    if (tid >= 2564) return;
    int plane = tid / 641, r = tid % 641;
    int y = (r <= 320) ? 0 : (r - 320);
    int x = (r <= 320) ? r : 0;
    size_t base = ((size_t)(plane * 321 + y) * 321 + x) * 96;
    bf16x8 z = {};
#pragma unroll
    for (int j = 0; j < 12; ++j) *(bf16x8*)&nhwc[base + j * 8] = z;
}

// ---------------------------------------------------------------------------
// K0c: NCHW f32 -> padded NHWC bf16 transpose. One block per (img,b,y,xhalf):
// 2*2*320*2 = 2560 blocks. Phase 1: coalesced f32x4 reads over x (per c),
// bf16 convert, LDS [c][x] stride 164 (8B-aligned s16x4 writes). Phase 2:
// transpose-read 8 ch per pixel, contiguous 16B global writes (pixel-major).
// ---------------------------------------------------------------------------
__global__ __launch_bounds__(256) void tpose(const float* __restrict__ f0w,
                                             const float* __restrict__ f1w,
                                             short* __restrict__ nhwc) {
    __shared__ short lds[96 * 164];
    int id = blockIdx.x;
    const int xh = id & 1; id >>= 1;
    const int y = id % 320; id /= 320;
    const int b = id & 1;
    const int img = id >> 1;
    const int t = threadIdx.x;
    const int x0 = xh * 160;

    const float* src = (img ? f1w : f0w) + (size_t)b * 96 * 102400 + y * 320 + x0;
#pragma unroll 5
    for (int v = t; v < 3840; v += 256) {         // 96c * 40 x-quads
        int x4 = v % 40, c = v / 40;
        f32x4 f = *(const f32x4*)(src + (size_t)c * 102400 + x4 * 4);
        s16x4 h;
#pragma unroll
        for (int j = 0; j < 4; ++j) h[j] = f2bf(f[j]);
        *(s16x4*)&lds[c * 164 + x4 * 4] = h;
    }
    __syncthreads();

    const size_t obase = ((size_t)((img * 2 + b) * 321 + (y + 1)) * 321 + (x0 + 1)) * 96;
    for (int ch = t; ch < 1920; ch += 256) {      // 160 px * 12 ch-octets
        int x = ch / 12, c8 = (ch % 12) * 8;
        bf16x8 o;
#pragma unroll
        for (int j = 0; j < 8; ++j) o[j] = lds[(c8 + j) * 164 + x];
        *(bf16x8*)&nhwc[obase + (size_t)x * 96 + c8] = o;
    }
}

// ---------------------------------------------------------------------------
// K1: per-m 64x64 sim via 3-term split-bf16 MFMA (hi*hi + hi*lo + lo*hi),
//     conf = softmax_l * softmax_s, conf write, argmax -> mconf/valid +
//     mk0/mk1 coords. One block per m, 4 waves; wave w owns rows w*16..w*16+15.
// ---------------------------------------------------------------------------
__global__ __launch_bounds__(256, 3) void stageA(const float* __restrict__ f0u,
                                                 const float* __restrict__ f1u,
                                                 const int* __restrict__ i_ids_c,
                                                 const int* __restrict__ j_ids_c,
                                                 float* __restrict__ out,
                                                 int* __restrict__ mkws) {
    __shared__ short h0s[6144], l0s[6144];   // f0: 64 rows x 96, hi/lo bf16
    __shared__ short h1s[6144], l1s[6144];   // f1
    __shared__ float Cpart[256];             // [wave][s] col partial sums
    __shared__ float rbv[4];
    __shared__ int   rbi[4];

    const int m = blockIdx.x;
    const int t = threadIdx.x;
    const int lane = t & 63, w = t >> 6;
    const int l15 = lane & 15, q = lane >> 4;

    // ---- stage f0/f1 into LDS as bf16 hi/lo split (RNE hi, RNE residual) ----
    const float* g0 = f0u + (size_t)m * 6144;
    const float* g1 = f1u + (size_t)m * 6144;
#pragma unroll
    for (int it = 0; it < 12; ++it) {
        const int i = it * 256 + t;           // uniform branch per iteration
        const bool first = (i < 1536);
        const int off = (first ? i : i - 1536) * 4;
        f32x4 v = *(const f32x4*)((first ? g0 : g1) + off);
        s16x4 hv, lv;
#pragma unroll
        for (int j = 0; j < 4; ++j) {
            __hip_bfloat16 hb = __float2bfloat16(v[j]);
            hv[j] = *reinterpret_cast<short*>(&hb);
            float r = v[j] - __bfloat162float(hb);
            __hip_bfloat16 lb = __float2bfloat16(r);
            lv[j] = *reinterpret_cast<short*>(&lb);
        }
        *(s16x4*)&(first ? h0s : h1s)[off] = hv;
        *(s16x4*)&(first ? l0s : l1s)[off] = lv;
    }
    __syncthreads();

    // ---- sim = f0 . f1^T via MFMA, 3-term split ----
    bf16x8 aH[3], aL[3];
    const int abase = (w * 16 + l15) * 96;
#pragma unroll
    for (int c = 0; c < 3; ++c) {
        aH[c] = *(const bf16x8*)&h0s[abase + c * 32 + q * 8];
        aL[c] = *(const bf16x8*)&l0s[abase + c * 32 + q * 8];
    }
    f32x4 acc[4] = {};
#pragma unroll
    for (int sj = 0; sj < 4; ++sj) {
        const int bbase = (sj * 16 + l15) * 96;
#pragma unroll
        for (int c = 0; c < 3; ++c) {
            bf16x8 bH = *(const bf16x8*)&h1s[bbase + c * 32 + q * 8];
            bf16x8 bL = *(const bf16x8*)&l1s[bbase + c * 32 + q * 8];
            acc[sj] = __builtin_amdgcn_mfma_f32_16x16x32_bf16(aH[c], bH, acc[sj], 0, 0, 0);
            acc[sj] = __builtin_amdgcn_mfma_f32_16x16x32_bf16(aH[c], bL, acc[sj], 0, 0, 0);
            acc[sj] = __builtin_amdgcn_mfma_f32_16x16x32_bf16(aL[c], bH, acc[sj], 0, 0, 0);
        }
    }

    // lane holds e[sj][r] for row = w*16 + q*4 + r, col s = sj*16 + l15
    float e[4][4];
    float rp[4] = {0.f, 0.f, 0.f, 0.f}, cp[4] = {0.f, 0.f, 0.f, 0.f};
#pragma unroll
    for (int sj = 0; sj < 4; ++sj)
#pragma unroll
        for (int r = 0; r < 4; ++r) {
            float v = __expf(acc[sj][r] * SIM_SCALE);
            e[sj][r] = v;
            rp[r] += v;
            cp[sj] += v;
        }
#pragma unroll
    for (int mk = 1; mk <= 8; mk <<= 1)
#pragma unroll
        for (int r = 0; r < 4; ++r) rp[r] += __shfl_xor(rp[r], mk);
#pragma unroll
    for (int mk = 16; mk <= 32; mk <<= 1)
#pragma unroll
        for (int sj = 0; sj < 4; ++sj) cp[sj] += __shfl_xor(cp[sj], mk);
    if (q == 0) {
#pragma unroll
        for (int sj = 0; sj < 4; ++sj) Cpart[w * 64 + sj * 16 + l15] = cp[sj];
    }
    __syncthreads();

    float ivr[4], ivc[4];
#pragma unroll
    for (int r = 0; r < 4; ++r) ivr[r] = 1.0f / rp[r];
#pragma unroll
    for (int sj = 0; sj < 4; ++sj) {
        const int s = sj * 16 + l15;
        ivc[sj] = 1.0f / (Cpart[s] + Cpart[64 + s] + Cpart[128 + s] + Cpart[192 + s]);
    }

    // conf write + thread-local argmax (tie -> lowest flat index, as jnp.argmax)
    float bestv = -1.0f;
    int besti = 0;
    float* cbase = out + (size_t)m * 4096;
#pragma unroll
    for (int sj = 0; sj < 4; ++sj) {
        const int s = sj * 16 + l15;
        const float is = ivc[sj];
#pragma unroll
        for (int r = 0; r < 4; ++r) {
            const int row = w * 16 + q * 4 + r;
            const float ev = e[sj][r];
            const float c = (ev * ivr[r]) * (ev * is);
            cbase[row * 64 + s] = c;
            const int fi = row * 64 + s;
            if (c > bestv || (c == bestv && fi < besti)) { bestv = c; besti = fi; }
        }
    }
#pragma unroll
    for (int mk = 1; mk <= 32; mk <<= 1) {
        float ov = __shfl_xor(bestv, mk);
        int   oi = __shfl_xor(besti, mk);
        if (ov > bestv || (ov == bestv && oi < besti)) { bestv = ov; besti = oi; }
    }
    if (lane == 0) { rbv[w] = bestv; rbi[w] = besti; }
    __syncthreads();
    if (t == 0) {
        float bv = rbv[0]; int bi = rbi[0];
#pragma unroll
        for (int g = 1; g < 4; ++g) {
            float v = rbv[g]; int idx = rbi[g];
            if (v > bv || (v == bv && idx < bi)) { bv = v; bi = idx; }
        }
        bool valid = bv > 0.01f;
        out[OFF_MCONF + m] = valid ? bv : 0.0f;
        out[OFF_VALID + m] = valid ? 1.0f : 0.0f;
        int il = bi >> 6, js = bi & 63;
        int ic0 = i_ids_c[m], jc0 = j_ids_c[m];
        mkws[m * 4 + 0] = (ic0 % 80) * 4 + (il & 7) - 4;   // mk0 x
        mkws[m * 4 + 1] = (ic0 / 80) * 4 + (il >> 3) - 4;  // mk0 y
        mkws[m * 4 + 2] = (jc0 % 80) * 4 + (js & 7) - 4;   // mk1 x
        mkws[m * 4 + 3] = (jc0 / 80) * 4 + (js >> 3) - 4;  // mk1 y
    }
}

// ---------------------------------------------------------------------------
// K2: fused gather + conv1(3x3,pad1) + conv2(3x3,valid) + conv3(1x1) + tanh.
// 16 matches per block. NHWC=1: gather reads padded NHWC bf16 (576B contig
// per (m,img,dy), no bounds checks, no convert). NHWC=0: legacy NCHW gather.
// ---------------------------------------------------------------------------
template <int NHWC>
__global__ __launch_bounds__(256, 2) void stageB(const float* __restrict__ w0whole,
                                                 const float* __restrict__ w1whole,
                                                 const short* __restrict__ nhwc,
                                                 const int* __restrict__ bids,
                                                 const int* __restrict__ mkws,
                                                 const short* __restrict__ w1b,
                                                 const short* __restrict__ w2b,
                                                 const float* __restrict__ w3,
                                                 float* __restrict__ out) {
    __shared__ short bufA[32000];        // 64 KB: patches, then conv1 output
    __shared__ float bufC[16 * 196];     // conv2 output (padded stride 196)
    __shared__ float xout[64];

    const int t = threadIdx.x;
    const int m0 = blockIdx.x * 16;
    const int lane = t & 63, wv = t >> 6;
    const int l16 = lane & 15, quad = lane >> 4;
    const int colb = wv * 48;

    // zero-slot (slot 9) per m
    for (int v = t; v < 16 * 200; v += 256) {
        int mm = v / 200, c = v % 200;
        bufA[mm * 2000 + 1800 + c] = 0;
    }
    if constexpr (NHWC) {
        // 96 segments (m,img,dy) x 36 16B-chunks; contiguous 576B per segment
        for (int ch = t; ch < 3456; ch += 256) {
            int seg = ch / 36, k8 = (ch - seg * 36) * 8;
            int dy = seg % 3;
            int mi = seg / 3;
            int img = mi & 1;
            int m_loc = mi >> 1;
            int mg = m0 + m_loc;
            int b = bids[mg];
            int mkx = mkws[mg * 4 + img * 2 + 0];
            int mky = mkws[mg * 4 + img * 2 + 1];
            int dx = k8 / 96;
            int c = k8 - dx * 96;
            const short* src = nhwc +
                (((size_t)((img * 2 + b) * 321 + (mky + dy)) * 321 + (mkx + dx)) * 96 + c);
            bf16x8 v = *(const bf16x8*)src;
            *(bf16x8*)&bufA[m_loc * 2000 + (dy * 3 + dx) * 200 + img * 96 + c] = v;
        }
    } else {
        // legacy NCHW gather: 9216 3-float row segments
        for (int seg = t; seg < 9216; seg += 256) {
            int c = seg % 96;
            int r = seg / 96;
            int dy = r % 3;
            int mi = r / 3;
            int img = mi & 1;
            int m_loc = mi >> 1;
            int mg = m0 + m_loc;
            int b = bids[mg];
            int mkx = mkws[mg * 4 + img * 2 + 0];
            int mky = mkws[mg * 4 + img * 2 + 1];
            int y = mky + dy - 1;
            const float* src = (img ? w1whole : w0whole) + (((size_t)b * 96 + c) * 320 + y) * 320;
            bool yok = (unsigned)y < 320u;
            short* dst = &bufA[m_loc * 2000 + dy * 3 * 200 + img * 96 + c];
#pragma unroll
            for (int dx = 0; dx < 3; ++dx) {
                int x = mkx + dx - 1;
                float v = (yok && (unsigned)x < 320u) ? src[x] : 0.0f;
                dst[dx * 200] = f2bf(v);
            }
        }
    }
    __syncthreads();

    // ---- conv1: GEMM rows=(m*9+p) 144, cols=oc 192, K=(q,ic) 1728 ----
    int mbase[9], py[9], px[9];
#pragma unroll
    for (int rt = 0; rt < 9; ++rt) {
        int row = rt * 16 + l16;
        int mm = row / 9;
        int p = row - mm * 9;
        mbase[rt] = mm * 2000;
        py[rt] = p / 3;
        px[rt] = p - py[rt] * 3;
    }
    f32x4 acc1[9][3] = {};
#pragma unroll
    for (int q = 0; q < 9; ++q) {
        const int qy = q / 3, qx = q % 3;
        int aoff[9];
#pragma unroll
        for (int rt = 0; rt < 9; ++rt) {
            int y = py[rt] + qy - 1, x = px[rt] + qx - 1;
            bool ok = ((unsigned)y < 3u) && ((unsigned)x < 3u);
            int slot = ok ? (y * 3 + x) : 9;
            aoff[rt] = mbase[rt] + slot * 200 + quad * 8;
        }
#pragma unroll
        for (int kk = 0; kk < 6; ++kk) {
            const int kg = q * 192 + kk * 32 + quad * 8;
            bf16x8 bfr[3];
#pragma unroll
            for (int ct = 0; ct < 3; ++ct) {
                int n = colb + ct * 16 + l16;
                bfr[ct] = *(const bf16x8*)(w1b + n * 1728 + kg);
            }
            bf16x8 afr[9];
#pragma unroll
            for (int rt = 0; rt < 9; ++rt)
                afr[rt] = *(const bf16x8*)&bufA[aoff[rt] + kk * 32];
#pragma unroll
            for (int rt = 0; rt < 9; ++rt)
#pragma unroll
                for (int ct = 0; ct < 3; ++ct)
                    acc1[rt][ct] = __builtin_amdgcn_mfma_f32_16x16x32_bf16(
                        afr[rt], bfr[ct], acc1[rt][ct], 0, 0, 0);
        }
    }
    __syncthreads();
    // leaky-relu, bf16, store as [row][oc] stride 200 (in-place over patches)
#pragma unroll
    for (int rt = 0; rt < 9; ++rt)
#pragma unroll
        for (int ct = 0; ct < 3; ++ct)
#pragma unroll
            for (int r = 0; r < 4; ++r) {
                int row = rt * 16 + quad * 4 + r;
                int col = colb + ct * 16 + l16;
                float v = acc1[rt][ct][r];
                v = (v > 0.f) ? v : 0.01f * v;
                bufA[row * 200 + col] = f2bf(v);
            }
    __syncthreads();

    // ---- conv2: rows=m 16, cols=oc2 192, K=(p,ic2) 1728 ----
    f32x4 acc2[3] = {};
#pragma unroll 6
    for (int ks = 0; ks < 54; ++ks) {
        int k = ks * 32 + quad * 8;
        int p = k / 192;
        int ic = k - p * 192;
        bf16x8 a = *(const bf16x8*)&bufA[l16 * 1800 + p * 200 + ic];
#pragma unroll
        for (int ct = 0; ct < 3; ++ct) {
            int n = colb + ct * 16 + l16;
            bf16x8 b = *(const bf16x8*)(w2b + n * 1728 + k);
            acc2[ct] = __builtin_amdgcn_mfma_f32_16x16x32_bf16(a, b, acc2[ct], 0, 0, 0);
        }
    }
#pragma unroll
    for (int ct = 0; ct < 3; ++ct)
#pragma unroll
        for (int r = 0; r < 4; ++r) {
            int mrow = quad * 4 + r;
            int col = colb + ct * 16 + l16;
            float v = acc2[ct][r];
            v = (v > 0.f) ? v : 0.01f * v;
            bufC[mrow * 196 + col] = v;
        }
    __syncthreads();

    // ---- conv3 (1x1, 4 out channels) ----
    if (t < 64) {
        int mloc = t >> 2, j = t & 3;
        const float* wr = w3 + j * 192;
        const float* xr = &bufC[mloc * 196];
        float d = 0.f;
        for (int c = 0; c < 192; ++c) d += xr[c] * wr[c];
        xout[t] = d;
    }
    __syncthreads();
    if (t < 16) {
        int mg = m0 + t;
        float s0x = tanhf(xout[t * 4 + 0]) * 0.5f;
        float s0y = tanhf(xout[t * 4 + 1]) * 0.5f;
        float s1x = tanhf(xout[t * 4 + 2]) * 0.5f;
        float s1y = tanhf(xout[t * 4 + 3]) * 0.5f;
        float mk0x = (float)mkws[mg * 4 + 0], mk0y = (float)mkws[mg * 4 + 1];
        float mk1x = (float)mkws[mg * 4 + 2], mk1y = (float)mkws[mg * 4 + 3];
        out[OFF_MK0 + mg * 2 + 0] = (mk0x + s0x) * 2.0f;
        out[OFF_MK0 + mg * 2 + 1] = (mk0y + s0y) * 2.0f;
        out[OFF_MK1 + mg * 2 + 0] = (mk1x + s1x) * 2.0f;
        out[OFF_MK1 + mg * 2 + 1] = (mk1y + s1y) * 2.0f;
    }
}

extern "C" void kernel_launch(void* const* d_in, const int* in_sizes, int n_in,
                              void* d_out, int out_size, void* d_ws, size_t ws_size,
                              hipStream_t stream) {
    const float* f0u = (const float*)d_in[0];
    const float* f1u = (const float*)d_in[1];
    const float* f0w = (const float*)d_in[2];
    const float* f1w = (const float*)d_in[3];
    const int* bids  = (const int*)d_in[4];
    const int* iids  = (const int*)d_in[5];
    const int* jids  = (const int*)d_in[6];
    const float* w1  = (const float*)d_in[7];
    const float* w2  = (const float*)d_in[8];
    const float* w3  = (const float*)d_in[9];
    float* out = (float*)d_out;
    char* ws = (char*)d_ws;
    int* mkws   = (int*)(ws + WS_MKWS);
    short* w1b  = (short*)(ws + WS_W1B);
    short* w2b  = (short*)(ws + WS_W2B);
    short* nhwc = (short*)(ws + WS_NHWC);
    const bool big = ws_size >= WS_NHWC + NHWC_BYTES;

    wprep<<<dim3(2592), dim3(256), 0, stream>>>(w1, w2, w1b, w2b);
    if (big) {
        zborder<<<dim3(11), dim3(256), 0, stream>>>(nhwc);
        tpose<<<dim3(2560), dim3(256), 0, stream>>>(f0w, f1w, nhwc);
    }
    stageA<<<dim3(8192), dim3(256), 0, stream>>>(f0u, f1u, iids, jids, out, mkws);
    if (big) {
        stageB<1><<<dim3(512), dim3(256), 0, stream>>>(f0w, f1w, nhwc, bids, mkws,
                                                       w1b, w2b, w3, out);
    } else {
        stageB<0><<<dim3(512), dim3(256), 0, stream>>>(f0w, f1w, nullptr, bids, mkws,
                                                       w1b, w2b, w3, out);
    }
}

// Round 3
// 664.924 us; speedup vs baseline: 1.2161x; 1.0006x over previous
//
#include <hip/hip_runtime.h>
#include <hip/hip_bf16.h>
#include <math.h>

typedef __attribute__((ext_vector_type(4))) float f32x4;
typedef __attribute__((ext_vector_type(8))) short bf16x8;
typedef __attribute__((ext_vector_type(4))) short s16x4;

#define M_TOT   8192
#define OFF_MCONF 33554432LL                 // 8192*4096
#define OFF_MK0   33562624LL
#define OFF_MK1   33579008LL
#define OFF_VALID 33595392LL
#define SIM_SCALE 0.10416666666666667f       // 1/(96*0.1)

// workspace layout
#define WS_MKWS   0
#define WS_W1B    131072
#define WS_W2B    794624
#define WS_NHWC   1458176ULL
#define NHWC_BYTES 79135488ULL               // 4 planes * 321*321*96 * 2B
// padded NHWC dims: [img*2+b][321][321][96] bf16, pixel (y+1, x+1)

__device__ __forceinline__ short f2bf(float v) {
    __hip_bfloat16 h = __float2bfloat16(v);
    return *reinterpret_cast<short*>(&h);
}

// ---------------------------------------------------------------------------
// K0: repack w1/w2 (oc,ic,ky,kx) f32 -> fragment-linear bf16 B-panels:
//   dst[((nt*216 + q*24 + c8) * 16 + l16) * 8 + e]  where oc = nt*16+l16,
//   ic = c8*8+e, q = ky*3+kx.  A wave's MFMA B-fragment load (16 lanes x 16B
//   x 4 quads) is then 1024B fully contiguous -> coalesced L2 hits instead of
//   64-line scatter.
// ---------------------------------------------------------------------------
__global__ void wprep(const float* __restrict__ w1, const float* __restrict__ w2,
                      short* __restrict__ o1, short* __restrict__ o2) {
    int i = blockIdx.x * 256 + threadIdx.x;
    if (i >= 2 * 331776) return;
    const float* src = (i < 331776) ? w1 : w2;
    short* dst       = (i < 331776) ? o1 : o2;
    int o = (i < 331776) ? i : i - 331776;
    int e   = o & 7;
    int l16 = (o >> 3) & 15;
    int u   = o >> 7;
    int c8  = u % 24;
    int q   = (u / 24) % 9;
    int nt  = u / 216;
    int oc  = nt * 16 + l16;
    int ic  = c8 * 8 + e;
    dst[o] = f2bf(src[oc * 1728 + ic * 9 + q]);
}

// ---------------------------------------------------------------------------
// K0b: zero the -1 border (y'==0 row and x'==0 column) of the NHWC buffer.
// ---------------------------------------------------------------------------
__global__ void zborder(short* __restrict__ nhwc) {
    int tid = blockIdx.x * 256 + threadIdx.x;
    if (tid >= 2564) return;
    int plane = tid / 641, r = tid % 641;
    int y = (r <= 320) ? 0 : (r - 320);
    int x = (r <= 320) ? r : 0;
    size_t base = ((size_t)(plane * 321 + y) * 321 + x) * 96;
    bf16x8 z = {};
#pragma unroll
    for (int j = 0; j < 12; ++j) *(bf16x8*)&nhwc[base + j * 8] = z;
}

// ---------------------------------------------------------------------------
// K0c: NCHW f32 -> padded NHWC bf16 transpose.
// ---------------------------------------------------------------------------
__global__ __launch_bounds__(256) void tpose(const float* __restrict__ f0w,
                                             const float* __restrict__ f1w,
                                             short* __restrict__ nhwc) {
    __shared__ short lds[96 * 164];
    int id = blockIdx.x;
    const int xh = id & 1; id >>= 1;
    const int y = id % 320; id /= 320;
    const int b = id & 1;
    const int img = id >> 1;
    const int t = threadIdx.x;
    const int x0 = xh * 160;

    const float* src = (img ? f1w : f0w) + (size_t)b * 96 * 102400 + y * 320 + x0;
#pragma unroll 5
    for (int v = t; v < 3840; v += 256) {         // 96c * 40 x-quads
        int x4 = v % 40, c = v / 40;
        f32x4 f = *(const f32x4*)(src + (size_t)c * 102400 + x4 * 4);
        s16x4 h;
#pragma unroll
        for (int j = 0; j < 4; ++j) h[j] = f2bf(f[j]);
        *(s16x4*)&lds[c * 164 + x4 * 4] = h;
    }
    __syncthreads();

    const size_t obase = ((size_t)((img * 2 + b) * 321 + (y + 1)) * 321 + (x0 + 1)) * 96;
    for (int ch = t; ch < 1920; ch += 256) {      // 160 px * 12 ch-octets
        int x = ch / 12, c8 = (ch % 12) * 8;
        bf16x8 o;
#pragma unroll
        for (int j = 0; j < 8; ++j) o[j] = lds[(c8 + j) * 164 + x];
        *(bf16x8*)&nhwc[obase + (size_t)x * 96 + c8] = o;
    }
}

// ---------------------------------------------------------------------------
// K1: per-m 64x64 sim via 3-term split-bf16 MFMA, conf = sm_l * sm_s,
//     argmax -> mconf/valid + mk coords.
// ---------------------------------------------------------------------------
__global__ __launch_bounds__(256, 3) void stageA(const float* __restrict__ f0u,
                                                 const float* __restrict__ f1u,
                                                 const int* __restrict__ i_ids_c,
                                                 const int* __restrict__ j_ids_c,
                                                 float* __restrict__ out,
                                                 int* __restrict__ mkws) {
    __shared__ short h0s[6144], l0s[6144];   // f0: 64 rows x 96, hi/lo bf16
    __shared__ short h1s[6144], l1s[6144];   // f1
    __shared__ float Cpart[256];             // [wave][s] col partial sums
    __shared__ float rbv[4];
    __shared__ int   rbi[4];

    const int m = blockIdx.x;
    const int t = threadIdx.x;
    const int lane = t & 63, w = t >> 6;
    const int l15 = lane & 15, q = lane >> 4;

    const float* g0 = f0u + (size_t)m * 6144;
    const float* g1 = f1u + (size_t)m * 6144;
#pragma unroll
    for (int it = 0; it < 12; ++it) {
        const int i = it * 256 + t;
        const bool first = (i < 1536);
        const int off = (first ? i : i - 1536) * 4;
        f32x4 v = *(const f32x4*)((first ? g0 : g1) + off);
        s16x4 hv, lv;
#pragma unroll
        for (int j = 0; j < 4; ++j) {
            __hip_bfloat16 hb = __float2bfloat16(v[j]);
            hv[j] = *reinterpret_cast<short*>(&hb);
            float r = v[j] - __bfloat162float(hb);
            __hip_bfloat16 lb = __float2bfloat16(r);
            lv[j] = *reinterpret_cast<short*>(&lb);
        }
        *(s16x4*)&(first ? h0s : h1s)[off] = hv;
        *(s16x4*)&(first ? l0s : l1s)[off] = lv;
    }
    __syncthreads();

    bf16x8 aH[3], aL[3];
    const int abase = (w * 16 + l15) * 96;
#pragma unroll
    for (int c = 0; c < 3; ++c) {
        aH[c] = *(const bf16x8*)&h0s[abase + c * 32 + q * 8];
        aL[c] = *(const bf16x8*)&l0s[abase + c * 32 + q * 8];
    }
    f32x4 acc[4] = {};
#pragma unroll
    for (int sj = 0; sj < 4; ++sj) {
        const int bbase = (sj * 16 + l15) * 96;
#pragma unroll
        for (int c = 0; c < 3; ++c) {
            bf16x8 bH = *(const bf16x8*)&h1s[bbase + c * 32 + q * 8];
            bf16x8 bL = *(const bf16x8*)&l1s[bbase + c * 32 + q * 8];
            acc[sj] = __builtin_amdgcn_mfma_f32_16x16x32_bf16(aH[c], bH, acc[sj], 0, 0, 0);
            acc[sj] = __builtin_amdgcn_mfma_f32_16x16x32_bf16(aH[c], bL, acc[sj], 0, 0, 0);
            acc[sj] = __builtin_amdgcn_mfma_f32_16x16x32_bf16(aL[c], bH, acc[sj], 0, 0, 0);
        }
    }

    float e[4][4];
    float rp[4] = {0.f, 0.f, 0.f, 0.f}, cp[4] = {0.f, 0.f, 0.f, 0.f};
#pragma unroll
    for (int sj = 0; sj < 4; ++sj)
#pragma unroll
        for (int r = 0; r < 4; ++r) {
            float v = __expf(acc[sj][r] * SIM_SCALE);
            e[sj][r] = v;
            rp[r] += v;
            cp[sj] += v;
        }
#pragma unroll
    for (int mk = 1; mk <= 8; mk <<= 1)
#pragma unroll
        for (int r = 0; r < 4; ++r) rp[r] += __shfl_xor(rp[r], mk);
#pragma unroll
    for (int mk = 16; mk <= 32; mk <<= 1)
#pragma unroll
        for (int sj = 0; sj < 4; ++sj) cp[sj] += __shfl_xor(cp[sj], mk);
    if (q == 0) {
#pragma unroll
        for (int sj = 0; sj < 4; ++sj) Cpart[w * 64 + sj * 16 + l15] = cp[sj];
    }
    __syncthreads();

    float ivr[4], ivc[4];
#pragma unroll
    for (int r = 0; r < 4; ++r) ivr[r] = 1.0f / rp[r];
#pragma unroll
    for (int sj = 0; sj < 4; ++sj) {
        const int s = sj * 16 + l15;
        ivc[sj] = 1.0f / (Cpart[s] + Cpart[64 + s] + Cpart[128 + s] + Cpart[192 + s]);
    }

    float bestv = -1.0f;
    int besti = 0;
    float* cbase = out + (size_t)m * 4096;
#pragma unroll
    for (int sj = 0; sj < 4; ++sj) {
        const int s = sj * 16 + l15;
        const float is = ivc[sj];
#pragma unroll
        for (int r = 0; r < 4; ++r) {
            const int row = w * 16 + q * 4 + r;
            const float ev = e[sj][r];
            const float c = (ev * ivr[r]) * (ev * is);
            cbase[row * 64 + s] = c;
            const int fi = row * 64 + s;
            if (c > bestv || (c == bestv && fi < besti)) { bestv = c; besti = fi; }
        }
    }
#pragma unroll
    for (int mk = 1; mk <= 32; mk <<= 1) {
        float ov = __shfl_xor(bestv, mk);
        int   oi = __shfl_xor(besti, mk);
        if (ov > bestv || (ov == bestv && oi < besti)) { bestv = ov; besti = oi; }
    }
    if (lane == 0) { rbv[w] = bestv; rbi[w] = besti; }
    __syncthreads();
    if (t == 0) {
        float bv = rbv[0]; int bi = rbi[0];
#pragma unroll
        for (int g = 1; g < 4; ++g) {
            float v = rbv[g]; int idx = rbi[g];
            if (v > bv || (v == bv && idx < bi)) { bv = v; bi = idx; }
        }
        bool valid = bv > 0.01f;
        out[OFF_MCONF + m] = valid ? bv : 0.0f;
        out[OFF_VALID + m] = valid ? 1.0f : 0.0f;
        int il = bi >> 6, js = bi & 63;
        int ic0 = i_ids_c[m], jc0 = j_ids_c[m];
        mkws[m * 4 + 0] = (ic0 % 80) * 4 + (il & 7) - 4;   // mk0 x
        mkws[m * 4 + 1] = (ic0 / 80) * 4 + (il >> 3) - 4;  // mk0 y
        mkws[m * 4 + 2] = (jc0 % 80) * 4 + (js & 7) - 4;   // mk1 x
        mkws[m * 4 + 3] = (jc0 / 80) * 4 + (js >> 3) - 4;  // mk1 y
    }
}

// ---------------------------------------------------------------------------
// K2: fused gather + conv1 + conv2 + conv3 + tanh. B-panels fragment-linear.
// ---------------------------------------------------------------------------
template <int NHWC>
__global__ __launch_bounds__(256, 2) void stageB(const float* __restrict__ w0whole,
                                                 const float* __restrict__ w1whole,
                                                 const short* __restrict__ nhwc,
                                                 const int* __restrict__ bids,
                                                 const int* __restrict__ mkws,
                                                 const short* __restrict__ w1b,
                                                 const short* __restrict__ w2b,
                                                 const float* __restrict__ w3,
                                                 float* __restrict__ out) {
    __shared__ short bufA[32000];        // 64 KB: patches, then conv1 output
    __shared__ float bufC[16 * 196];     // conv2 output (padded stride 196)
    __shared__ float xout[64];

    const int t = threadIdx.x;
    const int m0 = blockIdx.x * 16;
    const int lane = t & 63, wv = t >> 6;
    const int l16 = lane & 15, quad = lane >> 4;
    const int colb = wv * 48;
    const int wvu = __builtin_amdgcn_readfirstlane(wv);
    // per-wave fragment-linear B bases: wave covers oc-tiles wvu*3 .. wvu*3+2
    const short* w1base = w1b + (size_t)wvu * 3 * 27648;   // 216*128 = 27648/tile
    const short* w2base = w2b + (size_t)wvu * 3 * 27648;
    const int fragoff = (l16 << 3);

    // zero-slot (slot 9) per m
    for (int v = t; v < 16 * 200; v += 256) {
        int mm = v / 200, c = v % 200;
        bufA[mm * 2000 + 1800 + c] = 0;
    }
    if constexpr (NHWC) {
        // 96 segments (m,img,dy) x 36 16B-chunks; contiguous 576B per segment
        for (int ch = t; ch < 3456; ch += 256) {
            int seg = ch / 36, k8 = (ch - seg * 36) * 8;
            int dy = seg % 3;
            int mi = seg / 3;
            int img = mi & 1;
            int m_loc = mi >> 1;
            int mg = m0 + m_loc;
            int b = bids[mg];
            int mkx = mkws[mg * 4 + img * 2 + 0];
            int mky = mkws[mg * 4 + img * 2 + 1];
            int dx = k8 / 96;
            int c = k8 - dx * 96;
            const short* src = nhwc +
                (((size_t)((img * 2 + b) * 321 + (mky + dy)) * 321 + (mkx + dx)) * 96 + c);
            bf16x8 v = *(const bf16x8*)src;
            *(bf16x8*)&bufA[m_loc * 2000 + (dy * 3 + dx) * 200 + img * 96 + c] = v;
        }
    } else {
        for (int seg = t; seg < 9216; seg += 256) {
            int c = seg % 96;
            int r = seg / 96;
            int dy = r % 3;
            int mi = r / 3;
            int img = mi & 1;
            int m_loc = mi >> 1;
            int mg = m0 + m_loc;
            int b = bids[mg];
            int mkx = mkws[mg * 4 + img * 2 + 0];
            int mky = mkws[mg * 4 + img * 2 + 1];
            int y = mky + dy - 1;
            const float* src = (img ? w1whole : w0whole) + (((size_t)b * 96 + c) * 320 + y) * 320;
            bool yok = (unsigned)y < 320u;
            short* dst = &bufA[m_loc * 2000 + dy * 3 * 200 + img * 96 + c];
#pragma unroll
            for (int dx = 0; dx < 3; ++dx) {
                int x = mkx + dx - 1;
                float v = (yok && (unsigned)x < 320u) ? src[x] : 0.0f;
                dst[dx * 200] = f2bf(v);
            }
        }
    }
    __syncthreads();

    // ---- conv1: GEMM rows=(m*9+p) 144, cols=oc 192, K=(q,ic) 1728 ----
    int mbase[9], py[9], px[9];
#pragma unroll
    for (int rt = 0; rt < 9; ++rt) {
        int row = rt * 16 + l16;
        int mm = row / 9;
        int p = row - mm * 9;
        mbase[rt] = mm * 2000;
        py[rt] = p / 3;
        px[rt] = p - py[rt] * 3;
    }
    f32x4 acc1[9][3] = {};
#pragma unroll
    for (int q = 0; q < 9; ++q) {
        const int qy = q / 3, qx = q % 3;
        int aoff[9];
#pragma unroll
        for (int rt = 0; rt < 9; ++rt) {
            int y = py[rt] + qy - 1, x = px[rt] + qx - 1;
            bool ok = ((unsigned)y < 3u) && ((unsigned)x < 3u);
            int slot = ok ? (y * 3 + x) : 9;
            aoff[rt] = mbase[rt] + slot * 200 + quad * 8;
        }
#pragma unroll
        for (int kk = 0; kk < 6; ++kk) {
            const int kq = (q * 24 + kk * 4 + quad) << 7;   // fragment-linear chunk
            bf16x8 bfr[3];
#pragma unroll
            for (int ct = 0; ct < 3; ++ct)
                bfr[ct] = *(const bf16x8*)(w1base + ct * 27648 + kq + fragoff);
            bf16x8 afr[9];
#pragma unroll
            for (int rt = 0; rt < 9; ++rt)
                afr[rt] = *(const bf16x8*)&bufA[aoff[rt] + kk * 32];
#pragma unroll
            for (int rt = 0; rt < 9; ++rt)
#pragma unroll
                for (int ct = 0; ct < 3; ++ct)
                    acc1[rt][ct] = __builtin_amdgcn_mfma_f32_16x16x32_bf16(
                        afr[rt], bfr[ct], acc1[rt][ct], 0, 0, 0);
        }
    }
    __syncthreads();
    // leaky-relu, bf16, store as [row][oc] stride 200 (in-place over patches)
#pragma unroll
    for (int rt = 0; rt < 9; ++rt)
#pragma unroll
        for (int ct = 0; ct < 3; ++ct)
#pragma unroll
            for (int r = 0; r < 4; ++r) {
                int row = rt * 16 + quad * 4 + r;
                int col = colb + ct * 16 + l16;
                float v = acc1[rt][ct][r];
                v = (v > 0.f) ? v : 0.01f * v;
                bufA[row * 200 + col] = f2bf(v);
            }
    __syncthreads();

    // ---- conv2: rows=m 16, cols=oc2 192, K=(p,ic2) 1728 ----
    f32x4 acc2[3] = {};
#pragma unroll 6
    for (int ks = 0; ks < 54; ++ks) {
        int k = ks * 32 + quad * 8;
        int p = k / 192;
        int ic = k - p * 192;
        bf16x8 a = *(const bf16x8*)&bufA[l16 * 1800 + p * 200 + ic];
        const int kq = ((ks * 4 + quad) << 7) + fragoff;
#pragma unroll
        for (int ct = 0; ct < 3; ++ct) {
            bf16x8 b = *(const bf16x8*)(w2base + ct * 27648 + kq);
            acc2[ct] = __builtin_amdgcn_mfma_f32_16x16x32_bf16(a, b, acc2[ct], 0, 0, 0);
        }
    }
#pragma unroll
    for (int ct = 0; ct < 3; ++ct)
#pragma unroll
        for (int r = 0; r < 4; ++r) {
            int mrow = quad * 4 + r;
            int col = colb + ct * 16 + l16;
            float v = acc2[ct][r];
            v = (v > 0.f) ? v : 0.01f * v;
            bufC[mrow * 196 + col] = v;
        }
    __syncthreads();

    // ---- conv3 (1x1, 4 out channels) ----
    if (t < 64) {
        int mloc = t >> 2, j = t & 3;
        const float* wr = w3 + j * 192;
        const float* xr = &bufC[mloc * 196];
        float d = 0.f;
        for (int c = 0; c < 192; ++c) d += xr[c] * wr[c];
        xout[t] = d;
    }
    __syncthreads();
    if (t < 16) {
        int mg = m0 + t;
        float s0x = tanhf(xout[t * 4 + 0]) * 0.5f;
        float s0y = tanhf(xout[t * 4 + 1]) * 0.5f;
        float s1x = tanhf(xout[t * 4 + 2]) * 0.5f;
        float s1y = tanhf(xout[t * 4 + 3]) * 0.5f;
        float mk0x = (float)mkws[mg * 4 + 0], mk0y = (float)mkws[mg * 4 + 1];
        float mk1x = (float)mkws[mg * 4 + 2], mk1y = (float)mkws[mg * 4 + 3];
        out[OFF_MK0 + mg * 2 + 0] = (mk0x + s0x) * 2.0f;
        out[OFF_MK0 + mg * 2 + 1] = (mk0y + s0y) * 2.0f;
        out[OFF_MK1 + mg * 2 + 0] = (mk1x + s1x) * 2.0f;
        out[OFF_MK1 + mg * 2 + 1] = (mk1y + s1y) * 2.0f;
    }
}

extern "C" void kernel_launch(void* const* d_in, const int* in_sizes, int n_in,
                              void* d_out, int out_size, void* d_ws, size_t ws_size,
                              hipStream_t stream) {
    const float* f0u = (const float*)d_in[0];
    const float* f1u = (const float*)d_in[1];
    const float* f0w = (const float*)d_in[2];
    const float* f1w = (const float*)d_in[3];
    const int* bids  = (const int*)d_in[4];
    const int* iids  = (const int*)d_in[5];
    const int* jids  = (const int*)d_in[6];
    const float* w1  = (const float*)d_in[7];
    const float* w2  = (const float*)d_in[8];
    const float* w3  = (const float*)d_in[9];
    float* out = (float*)d_out;
    char* ws = (char*)d_ws;
    int* mkws   = (int*)(ws + WS_MKWS);
    short* w1b  = (short*)(ws + WS_W1B);
    short* w2b  = (short*)(ws + WS_W2B);
    short* nhwc = (short*)(ws + WS_NHWC);
    const bool big = ws_size >= WS_NHWC + NHWC_BYTES;

    wprep<<<dim3(2592), dim3(256), 0, stream>>>(w1, w2, w1b, w2b);
    if (big) {
        zborder<<<dim3(11), dim3(256), 0, stream>>>(nhwc);
        tpose<<<dim3(2560), dim3(256), 0, stream>>>(f0w, f1w, nhwc);
    }
    stageA<<<dim3(8192), dim3(256), 0, stream>>>(f0u, f1u, iids, jids, out, mkws);
    if (big) {
        stageB<1><<<dim3(512), dim3(256), 0, stream>>>(f0w, f1w, nhwc, bids, mkws,
                                                       w1b, w2b, w3, out);
    } else {
        stageB<0><<<dim3(512), dim3(256), 0, stream>>>(f0w, f1w, nullptr, bids, mkws,
                                                       w1b, w2b, w3, out);
    }
}